// Round 4
// baseline (56.080 us; speedup 1.0000x reference)
//
#include <hip/hip_runtime.h>

// Sinusoidal oscillator with FM: out[b,n] = sin(2*pi * exclusive_cumsum_n(f0_rev*(1+mod_env*amt)))
// R4: f32 per-element math (increments + local prefix + fract + hw sin), f64 only for
//     the cross-thread/cross-chunk scan; VPT=16 to halve scan overhead; plain stores
//     (NT stores amplified WRITE_SIZE 131->150MB in R3 and didn't keep input resident).

constexpr int BLOCK = 1024;   // one block per row
constexpr int VPT   = 16;     // values per thread per chunk
constexpr int NW    = BLOCK / 64;  // 16 waves

typedef float f32x4 __attribute__((ext_vector_type(4)));

__global__ __launch_bounds__(BLOCK) void osc_kernel(
    const float* __restrict__ freq,        // [B]
    const float* __restrict__ mod_env,     // [B, N]
    const float* __restrict__ mod_amount,  // [B]
    float* __restrict__ out,               // [B, N]
    int N)
{
    const int row  = blockIdx.x;
    const int tid  = threadIdx.x;
    const int lane = tid & 63;
    const int wid  = tid >> 6;

    __shared__ double s_wsum[2][NW];      // double-buffered per-wave chunk sums

    const double f0rev = (20.0 + 1980.0 * (double)freq[row]) / 48000.0;  // rev/sample
    const double amt   = -1.0 + 3.0 * (double)mod_amount[row];
    const double kd    = f0rev * amt;
    const float  kf    = (float)kd;
    const float  f0f   = (float)f0rev;

    const float* __restrict__ rowp = mod_env + (size_t)row * N;
    float* __restrict__ outp       = out     + (size_t)row * N;

    const int chunk  = BLOCK * VPT;       // 16384
    const int nchunk = N / chunk;         // 4

    double carry = 0.0;

    // Prefetch chunk 0 (4x float4 = 64B/lane)
    f32x4 cur0, cur1, cur2, cur3;
    {
        const float* p = rowp + tid * VPT;
        cur0 = *(const f32x4*)(p);
        cur1 = *(const f32x4*)(p + 4);
        cur2 = *(const f32x4*)(p + 8);
        cur3 = *(const f32x4*)(p + 12);
    }

    for (int c = 0; c < nchunk; ++c) {
        f32x4 nxt0 = cur0, nxt1 = cur1, nxt2 = cur2, nxt3 = cur3;
        if (c + 1 < nchunk) {
            const float* p = rowp + (size_t)(c + 1) * chunk + tid * VPT;
            nxt0 = *(const f32x4*)(p);
            nxt1 = *(const f32x4*)(p + 4);
            nxt2 = *(const f32x4*)(p + 8);
            nxt3 = *(const f32x4*)(p + 12);
        }

        // f32 increments + exclusive local prefix (all compile-time indexed -> regs)
        float vv[VPT] = { cur0.x, cur0.y, cur0.z, cur0.w,
                          cur1.x, cur1.y, cur1.z, cur1.w,
                          cur2.x, cur2.y, cur2.z, cur2.w,
                          cur3.x, cur3.y, cur3.z, cur3.w };
        float lv[VPT];
        float s = 0.0f;
        #pragma unroll
        for (int i = 0; i < VPT; ++i) {
            float vi = fmaf(vv[i], kf, f0f);
            lv[i] = s;
            s += vi;
        }

        // Cross-thread scan of per-thread chunk sums, f64 (exact over the row)
        double tsum = (double)s;
        double x = tsum;
        #pragma unroll
        for (int off = 1; off < 64; off <<= 1) {
            double y = __shfl_up(x, off, 64);
            if (lane >= off) x += y;
        }

        if (lane == 63) s_wsum[c & 1][wid] = x;
        __syncthreads();   // the only barrier this chunk

        // Every wave redundantly scans the 16 wave sums
        double w = (lane < NW) ? s_wsum[c & 1][lane] : 0.0;
        #pragma unroll
        for (int off = 1; off < NW; off <<= 1) {
            double y = __shfl_up(w, off, 64);
            if (lane >= off) w += y;
        }
        double total = __shfl(w, NW - 1, 64);
        double exc   = __shfl(w, (wid > 0 ? wid - 1 : 0), 64);
        if (wid == 0) exc = 0.0;

        double phase = carry + exc + (x - tsum);   // exclusive base (revolutions)
        carry += total;

        // f32 fractional base; per-element add + fract + hw sin
        float bf = (float)(phase - floor(phase));

        float o[VPT];
        #pragma unroll
        for (int i = 0; i < VPT; ++i) {
            float pf = bf + lv[i];                 // < 3 rev
            pf = pf - floorf(pf);                  // [0,1)
            o[i] = __builtin_amdgcn_sinf(pf);      // v_sin_f32, input in revolutions
        }

        float* q = outp + (size_t)c * chunk + tid * VPT;
        *(f32x4*)(q)      = (f32x4){ o[0],  o[1],  o[2],  o[3]  };
        *(f32x4*)(q + 4)  = (f32x4){ o[4],  o[5],  o[6],  o[7]  };
        *(f32x4*)(q + 8)  = (f32x4){ o[8],  o[9],  o[10], o[11] };
        *(f32x4*)(q + 12) = (f32x4){ o[12], o[13], o[14], o[15] };

        cur0 = nxt0; cur1 = nxt1; cur2 = nxt2; cur3 = nxt3;
    }
}

extern "C" void kernel_launch(void* const* d_in, const int* in_sizes, int n_in,
                              void* d_out, int out_size, void* d_ws, size_t ws_size,
                              hipStream_t stream) {
    const float* freq       = (const float*)d_in[1];
    const float* mod_env    = (const float*)d_in[2];
    const float* mod_amount = (const float*)d_in[3];
    float* out = (float*)d_out;

    const int B = in_sizes[1];              // 512
    const int N = in_sizes[2] / B;          // 65536

    osc_kernel<<<B, BLOCK, 0, stream>>>(freq, mod_env, mod_amount, out, N);
}

// Round 5
// 46.075 us; speedup vs baseline: 1.2171x; 1.2171x over previous
//
#include <hip/hip_runtime.h>

// Sinusoidal oscillator with FM: out[b,n] = sin(2*pi * exclusive_cumsum_n(f0_rev*(1+mod_env*amt)))
// R5: fully DENSE global accesses — each wave owns contiguous 512-elem span/chunk,
//     lane l handles float4 at 4*l and 4*l+256 (16B lane stride: 1 instruction = 1KB,
//     16 fully-covered cache lines, vs 32 half-covered lines with the old 32B-stride
//     layout). Two interleaved f64 wave scans (span0/span1). Single barrier per chunk.

constexpr int BLOCK = 1024;        // one block per row, 16 waves
constexpr int VPT   = 8;           // elems per thread per chunk
constexpr int NW    = BLOCK / 64;  // 16 waves
constexpr int WELEM = 64 * VPT;    // 512 elems per wave per chunk

typedef float f32x4 __attribute__((ext_vector_type(4)));

__global__ __launch_bounds__(BLOCK) void osc_kernel(
    const float* __restrict__ freq,        // [B]
    const float* __restrict__ mod_env,     // [B, N]
    const float* __restrict__ mod_amount,  // [B]
    float* __restrict__ out,               // [B, N]
    int N)
{
    const int row  = blockIdx.x;
    const int tid  = threadIdx.x;
    const int lane = tid & 63;
    const int wid  = tid >> 6;

    __shared__ double s_wsum[2][NW];      // double-buffered per-wave chunk sums

    const double f0rev = (20.0 + 1980.0 * (double)freq[row]) / 48000.0;  // rev/sample
    const double amt   = -1.0 + 3.0 * (double)mod_amount[row];
    const float  kf    = (float)(f0rev * amt);
    const float  f0f   = (float)f0rev;

    const int chunk  = BLOCK * VPT;       // 8192
    const int nchunk = N / chunk;         // 8

    // Dense per-wave pointers: lane stride 16B within the wave's contiguous span
    const float* __restrict__ wload  = mod_env + (size_t)row * N + wid * WELEM + 4 * lane;
    float*       __restrict__ wstore = out     + (size_t)row * N + wid * WELEM + 4 * lane;

    double carry = 0.0;

    // Prefetch chunk 0: two dense spans (base, base+256)
    f32x4 curA = *(const f32x4*)(wload);
    f32x4 curB = *(const f32x4*)(wload + 256);

    for (int c = 0; c < nchunk; ++c) {
        f32x4 nxtA = curA, nxtB = curB;
        if (c + 1 < nchunk) {
            const float* p = wload + (size_t)(c + 1) * chunk;
            nxtA = *(const f32x4*)(p);
            nxtB = *(const f32x4*)(p + 256);
        }

        // f32 per-element increments
        float va0 = fmaf(curA.x, kf, f0f), va1 = fmaf(curA.y, kf, f0f);
        float va2 = fmaf(curA.z, kf, f0f), va3 = fmaf(curA.w, kf, f0f);
        float vb0 = fmaf(curB.x, kf, f0f), vb1 = fmaf(curB.y, kf, f0f);
        float vb2 = fmaf(curB.z, kf, f0f), vb3 = fmaf(curB.w, kf, f0f);

        float sa = (va0 + va1) + (va2 + va3);
        float sb = (vb0 + vb1) + (vb2 + vb3);

        // Two interleaved f64 wave scans (span0 sums, span1 sums)
        double xa = (double)sa, xb = (double)sb;
        #pragma unroll
        for (int off = 1; off < 64; off <<= 1) {
            double ya = __shfl_up(xa, off, 64);
            double yb = __shfl_up(xb, off, 64);
            if (lane >= off) { xa += ya; xb += yb; }
        }
        double Ta = __shfl(xa, 63, 64);   // span0 wave total

        if (lane == 63) s_wsum[c & 1][wid] = xa + xb;
        __syncthreads();   // the only barrier this chunk

        // Redundant cross-wave scan of the 16 wave sums
        double w = (lane < NW) ? s_wsum[c & 1][lane] : 0.0;
        #pragma unroll
        for (int off = 1; off < NW; off <<= 1) {
            double y = __shfl_up(w, off, 64);
            if (lane >= off) w += y;
        }
        double total = __shfl(w, NW - 1, 64);
        double exc   = __shfl(w, (wid > 0 ? wid - 1 : 0), 64);
        if (wid == 0) exc = 0.0;

        double base = carry + exc;
        carry += total;

        // Exclusive phase bases (revolutions) for the two spans
        double ph0 = base + (xa - (double)sa);
        double ph1 = base + Ta + (xb - (double)sb);

        float bf0 = (float)(ph0 - floor(ph0));
        float bf1 = (float)(ph1 - floor(ph1));

        f32x4 oA, oB;
        {
            float pf, fr;
            pf = bf0;
            fr = pf - floorf(pf); oA.x = __builtin_amdgcn_sinf(fr); pf += va0;
            fr = pf - floorf(pf); oA.y = __builtin_amdgcn_sinf(fr); pf += va1;
            fr = pf - floorf(pf); oA.z = __builtin_amdgcn_sinf(fr); pf += va2;
            fr = pf - floorf(pf); oA.w = __builtin_amdgcn_sinf(fr);
            pf = bf1;
            fr = pf - floorf(pf); oB.x = __builtin_amdgcn_sinf(fr); pf += vb0;
            fr = pf - floorf(pf); oB.y = __builtin_amdgcn_sinf(fr); pf += vb1;
            fr = pf - floorf(pf); oB.z = __builtin_amdgcn_sinf(fr); pf += vb2;
            fr = pf - floorf(pf); oB.w = __builtin_amdgcn_sinf(fr);
        }

        // Dense stores
        float* q = wstore + (size_t)c * chunk;
        *(f32x4*)(q)       = oA;
        *(f32x4*)(q + 256) = oB;

        curA = nxtA; curB = nxtB;
    }
}

extern "C" void kernel_launch(void* const* d_in, const int* in_sizes, int n_in,
                              void* d_out, int out_size, void* d_ws, size_t ws_size,
                              hipStream_t stream) {
    const float* freq       = (const float*)d_in[1];
    const float* mod_env    = (const float*)d_in[2];
    const float* mod_amount = (const float*)d_in[3];
    float* out = (float*)d_out;

    const int B = in_sizes[1];              // 512
    const int N = in_sizes[2] / B;          // 65536

    osc_kernel<<<B, BLOCK, 0, stream>>>(freq, mod_env, mod_amount, out, N);
}